// Round 16
// baseline (132.172 us; speedup 1.0000x reference)
//
#include <hip/hip_runtime.h>
#include <hip/hip_bf16.h>

#define WDIM 512
#define CHN  512
#define NB   32
#define SZ   64
#define MTOT 4096   // SZ*SZ

typedef __attribute__((ext_vector_type(4))) float f32x4;
typedef __attribute__((ext_vector_type(8))) short short8;
typedef __attribute__((ext_vector_type(4))) int   int4v;
typedef __attribute__((ext_vector_type(4))) unsigned int uint4v;

__device__ __forceinline__ unsigned pack_bf(float a, float b) {
    union { __hip_bfloat16 h; unsigned short u; } x, y;
    x.h = __float2bfloat16(a); y.h = __float2bfloat16(b);
    return (unsigned)x.u | ((unsigned)y.u << 16);
}
__device__ __forceinline__ float lo16f(unsigned u) {
    union { unsigned x; float f; } t; t.x = u << 16; return t.f;
}
__device__ __forceinline__ float hi16f(unsigned u) {
    union { unsigned x; float f; } t; t.x = u & 0xffff0000u; return t.f;
}

// ---------------- prep: affine reduction (inline) + packed bf16 tables + weight cvt ----------------
__global__ __launch_bounds__(512) void prep_kernel(
    const float* __restrict__ win,
    const float* __restrict__ affine_w,
    const float* __restrict__ affine_b,
    const float* __restrict__ freqs,
    const float* __restrict__ phases,
    const float* __restrict__ wsrc,
    unsigned* __restrict__ SCA, unsigned* __restrict__ SCB,
    __hip_bfloat16* __restrict__ wbf)
{
    const int b = blockIdx.x;
    const int tid = threadIdx.x;
    if (b < NB * 64) {
        const int n = b >> 6;
        const int w = b & 63;
        __shared__ float red[8][4];
        __shared__ float par[4];

        float wv = win[n * WDIM + tid];
        float p0 = wv * affine_w[0 * WDIM + tid];
        float p1 = wv * affine_w[1 * WDIM + tid];
        float p2 = wv * affine_w[2 * WDIM + tid];
        float p3 = wv * affine_w[3 * WDIM + tid];
        #pragma unroll
        for (int off = 32; off >= 1; off >>= 1) {
            p0 += __shfl_down(p0, off);
            p1 += __shfl_down(p1, off);
            p2 += __shfl_down(p2, off);
            p3 += __shfl_down(p3, off);
        }
        const int wave = tid >> 6;
        if ((tid & 63) == 0) {
            red[wave][0] = p0; red[wave][1] = p1;
            red[wave][2] = p2; red[wave][3] = p3;
        }
        __syncthreads();
        if (tid == 0) {
            const float gain = 0.04419417382415922f; // 1/sqrt(512)
            float t[4];
            #pragma unroll
            for (int j = 0; j < 4; ++j) {
                float s = 0.0f;
                #pragma unroll
                for (int v = 0; v < 8; ++v) s += red[v][j];
                t[j] = s * gain + affine_b[j];
            }
            float inv = 1.0f / sqrtf(t[0] * t[0] + t[1] * t[1]);
            float c = t[0] * inv, s = t[1] * inv, tx = t[2] * inv, ty = t[3] * inv;
            par[0] = c;
            par[1] = s;
            par[2] = -c * tx + s * ty;
            par[3] = -s * tx - c * ty;
        }
        __syncthreads();
        const float c_ = par[0], s_ = par[1], tr0 = par[2], tr1 = par[3];
        const int c = tid;
        float fx = freqs[c * 2 + 0], fy = freqs[c * 2 + 1];
        float frx = fx * c_ + fy * s_;
        float fry = -fx * s_ + fy * c_;
        float ph = phases[c] + fx * tr0 + fy * tr1;
        float r = sqrtf(frx * frx + fry * fry);
        float amp = 1.0f - (r - 2.0f) * (1.0f / 30.0f); // (r-BW)/(SR/2-BW)
        amp = fminf(fmaxf(amp, 0.0f), 1.0f);
        float xs = (float)(2 * w + 1) * (1.0f / 128.0f) - 0.5f; // == ys_w
        size_t idx = ((size_t)(n * 64 + w)) * CHN + c;
        float sA = amp * __builtin_amdgcn_sinf(xs * frx);
        float cA = amp * __builtin_amdgcn_cosf(xs * frx);
        float bb = xs * fry + ph;
        SCA[idx] = pack_bf(sA, cA);
        SCB[idx] = pack_bf(__builtin_amdgcn_sinf(bb), __builtin_amdgcn_cosf(bb));
    } else {
        int i = (b - NB * 64) * 512 + tid;
        wbf[i] = __float2bfloat16(wsrc[i] * 0.04419417382415922f);
    }
}

// ---------------- fused features + GEMM: 256x256 tile, phase-interleaved schedule ----------------
// 512 thr = 8 waves (2m x 4k), wave tile 128m x 64k, acc[4][8] = 128 VGPR.
// As/Bs double-buffered (128 KB LDS, 1 block/CU, 2 waves/SIMD).
// Per kc, 2 phases: {12 ds_reads; aux; lgkm(0); barrier; setprio; 32 MFMA}.
//   aux(kk0) = stage(t+1) DMA + loadT(t+1);  aux(kk1) = features(t+1) -> As[nxt].
// No vmcnt drain anywhere: features' implicit wait on loadT (newer in FIFO) retires
// stage one full phase after issue. 256-row m-tile => per-thread w fixed (w = rb):
// feature VALU and table bytes halved vs the 128-row tile.
__global__ __launch_bounds__(512, 2) void fused_kernel(
    const unsigned* __restrict__ SCA, const unsigned* __restrict__ SCB,
    const __hip_bfloat16* __restrict__ wbf,
    float* __restrict__ out)
{
    __shared__ __align__(16) __hip_bfloat16 As[2][256 * 64]; // 64 KB, swizzled
    __shared__ __align__(16) __hip_bfloat16 Bs[2][256 * 64]; // 64 KB, swizzled

    // XCD-bijective swizzle: 1024 blocks = 8 XCDs x 128; n-major within XCD
    const int bid  = blockIdx.x;
    const int orig = (bid & 7) * 128 + (bid >> 3);
    const int n  = orig >> 5;
    const int om = orig & 31;
    const int kb = (om >> 4) * 256;
    const int mb = (om & 15) * 256;
    const int h0 = mb >> 6;          // 4 h-rows: h0..h0+3

    const int tid = threadIdx.x;
    const int lane = tid & 63;
    const int wid  = tid >> 6;        // 0..7
    const int ln15 = lane & 15;
    const int hi4  = lane >> 4;
    const int wm   = (wid >> 2) * 128; // wave m offset
    const int wk   = (wid & 3) * 64;   // wave k offset

    const int cc0 = (tid & 7) * 8;    // c-subchunk within 64
    const int rb  = tid >> 3;         // 0..63 == w row (fixed per thread)

    const unsigned* pA = SCA + ((size_t)(n * 64 + rb)) * CHN + cc0;
    const unsigned* pB = SCB + ((size_t)(n * 64 + h0)) * CHN + cc0;

    auto stageB = [&](int t) {
        const int c0 = t * 64;
        char* base = (char*)Bs[t & 1];
        #pragma unroll
        for (int u = 0; u < 4; ++u) {
            int unit = u * 512 + tid;
            int row = unit >> 3;
            int cbyte = ((unit & 7) << 4) ^ ((row & 7) << 4);
            const __hip_bfloat16* src = wbf + (size_t)(kb + row) * CHN + c0 + (cbyte >> 1);
            char* ldsbase = base + (u * 512 + (wid << 6)) * 16; // wave-uniform
            __builtin_amdgcn_global_load_lds(
                (const __attribute__((address_space(1))) unsigned int*)src,
                (__attribute__((address_space(3))) unsigned int*)ldsbase, 16, 0, 0);
        }
    };

    // table registers for features(t): A (w=rb) 2x uint4, B (4 h-rows) 8x uint4
    uint4v A0, A1, B0[4], B1[4];
    auto loadT = [&](int c0) {
        A0 = *(const uint4v*)(pA + c0); A1 = *(const uint4v*)(pA + c0 + 4);
        #pragma unroll
        for (int i = 0; i < 4; ++i) {
            B0[i] = *(const uint4v*)(pB + (size_t)i * CHN + c0);
            B1[i] = *(const uint4v*)(pB + (size_t)i * CHN + c0 + 4);
        }
    };

    auto features = [&](int t) {
        char* abase = (char*)As[t & 1];
        #pragma unroll
        for (int i = 0; i < 4; ++i) {
            int m = rb + i * 64;     // h-row = h0+i, w = rb
            union { __hip_bfloat16 h[8]; int4v v; } tt;
            #pragma unroll
            for (int j = 0; j < 4; ++j)
                tt.h[j] = __float2bfloat16(
                    lo16f(A0[j]) * hi16f(B0[i][j]) + hi16f(A0[j]) * lo16f(B0[i][j]));
            #pragma unroll
            for (int j = 0; j < 4; ++j)
                tt.h[4 + j] = __float2bfloat16(
                    lo16f(A1[j]) * hi16f(B1[i][j]) + hi16f(A1[j]) * lo16f(B1[i][j]));
            *(int4v*)(abase + m * 128 + ((cc0 * 2) ^ ((m & 7) << 4))) = tt.v;
        }
    };

    f32x4 acc[4][8];
    #pragma unroll
    for (int a = 0; a < 4; ++a)
        #pragma unroll
        for (int b = 0; b < 8; ++b)
            acc[a][b] = (f32x4)0.0f;

    // ---- prologue ----
    stageB(0);
    loadT(0);        // newer than stage(0): features(0)'s wait retires stage(0) too
    features(0);
    stageB(1);
    loadT(64);
    __builtin_amdgcn_sched_barrier(0);
    asm volatile("s_waitcnt lgkmcnt(0)" ::: "memory"); // As(0) writes done
    __builtin_amdgcn_s_barrier();
    __builtin_amdgcn_sched_barrier(0);

    // ---- main loop: 2 phases per kc, no vmcnt drains ----
    #pragma unroll 1
    for (int t = 0; t < 8; ++t) {
        const char* bsb = (const char*)Bs[t & 1];
        const char* asb = (const char*)As[t & 1];
        #pragma unroll
        for (int kk = 0; kk < 2; ++kk) {
            short8 wf[4], ff[8];
            #pragma unroll
            for (int ki = 0; ki < 4; ++ki) {
                int row = wk + ki * 16 + ln15;
                wf[ki] = *(const short8*)(bsb + row * 128 +
                          (((kk * 32 + hi4 * 8) * 2) ^ ((row & 7) << 4)));
            }
            #pragma unroll
            for (int mj = 0; mj < 8; ++mj) {
                int m = wm + mj * 16 + ln15;
                ff[mj] = *(const short8*)(asb + m * 128 +
                          (((kk * 32 + hi4 * 8) * 2) ^ ((m & 7) << 4)));
            }
            if (kk == 0) {
                if (t < 7) { stageB(t + 1); loadT((t + 1) * 64); }
            } else {
                if (t < 7) features(t + 1); // waits loadT(t+1) -> retires stage(t+1)
            }
            __builtin_amdgcn_sched_barrier(0);
            asm volatile("s_waitcnt lgkmcnt(0)" ::: "memory"); // my reads + my writes
            __builtin_amdgcn_s_barrier();
            __builtin_amdgcn_sched_barrier(0);
            __builtin_amdgcn_s_setprio(1);
            #pragma unroll
            for (int ki = 0; ki < 4; ++ki)
                #pragma unroll
                for (int mj = 0; mj < 8; ++mj)
                    acc[ki][mj] = __builtin_amdgcn_mfma_f32_16x16x32_bf16(
                        wf[ki], ff[mj], acc[ki][mj], 0, 0, 0);
            __builtin_amdgcn_s_setprio(0);
            __builtin_amdgcn_sched_barrier(0);
        }
    }

    // ---- epilogue: out[n][k][hw], D col (ln15) = m -> coalesced ----
    #pragma unroll
    for (int ki = 0; ki < 4; ++ki) {
        #pragma unroll
        for (int mj = 0; mj < 8; ++mj) {
            int kg = kb + wk + ki * 16 + hi4 * 4;
            int mg = mb + wm + mj * 16 + ln15;
            float* op = out + ((size_t)n * CHN + kg) * MTOT + mg;
            #pragma unroll
            for (int r = 0; r < 4; ++r)
                op[(size_t)r * MTOT] = acc[ki][mj][r];
        }
    }
}

extern "C" void kernel_launch(void* const* d_in, const int* in_sizes, int n_in,
                              void* d_out, int out_size, void* d_ws, size_t ws_size,
                              hipStream_t stream) {
    const float* w        = (const float*)d_in[0];
    const float* affine_w = (const float*)d_in[1];
    const float* affine_b = (const float*)d_in[2];
    const float* weight   = (const float*)d_in[3];
    const float* freqs    = (const float*)d_in[4];
    const float* phases   = (const float*)d_in[5];
    float* out = (float*)d_out;

    char* ws = (char*)d_ws;
    __hip_bfloat16* wbf = (__hip_bfloat16*)(ws);                 // 512 KB
    unsigned* SCA = (unsigned*)(ws + (1u << 20));                // 4 MB
    unsigned* SCB = (unsigned*)(ws + (1u << 20) + (4u << 20));   // 4 MB

    prep_kernel<<<NB * 64 + (CHN * CHN) / 512, 512, 0, stream>>>(
        w, affine_w, affine_b, freqs, phases, weight, SCA, SCB, wbf);

    fused_kernel<<<1024, 512, 0, stream>>>(SCA, SCB, wbf, out);
}

// Round 17
// 102.540 us; speedup vs baseline: 1.2890x; 1.2890x over previous
//
#include <hip/hip_runtime.h>
#include <hip/hip_bf16.h>

#define WDIM 512
#define CHN  512
#define NB   32
#define SZ   64
#define MTOT 4096   // SZ*SZ

typedef __attribute__((ext_vector_type(4))) float f32x4;
typedef __attribute__((ext_vector_type(8))) short short8;
typedef __attribute__((ext_vector_type(4))) int   int4v;
typedef __attribute__((ext_vector_type(4))) unsigned int uint4v;

__device__ __forceinline__ unsigned pack_bf(float a, float b) {
    union { __hip_bfloat16 h; unsigned short u; } x, y;
    x.h = __float2bfloat16(a); y.h = __float2bfloat16(b);
    return (unsigned)x.u | ((unsigned)y.u << 16);
}
__device__ __forceinline__ float lo16f(unsigned u) {
    union { unsigned x; float f; } t; t.x = u << 16; return t.f;
}
__device__ __forceinline__ float hi16f(unsigned u) {
    union { unsigned x; float f; } t; t.x = u & 0xffff0000u; return t.f;
}

// ---------------- setup: per-batch affine+norm -> per-(n,c) params (computed ONCE) ----------------
__global__ __launch_bounds__(512) void setup_kernel(
    const float* __restrict__ win,
    const float* __restrict__ affine_w,
    const float* __restrict__ affine_b,
    const float* __restrict__ freqs,
    const float* __restrict__ phases,
    float* __restrict__ frx_o, float* __restrict__ fry_o,
    float* __restrict__ pha_o, float* __restrict__ amp_o)
{
    const int n = blockIdx.x;
    const int tid = threadIdx.x;
    __shared__ float red[8][4];
    __shared__ float par[4];

    float wv = win[n * WDIM + tid];
    float p0 = wv * affine_w[0 * WDIM + tid];
    float p1 = wv * affine_w[1 * WDIM + tid];
    float p2 = wv * affine_w[2 * WDIM + tid];
    float p3 = wv * affine_w[3 * WDIM + tid];
    #pragma unroll
    for (int off = 32; off >= 1; off >>= 1) {
        p0 += __shfl_down(p0, off);
        p1 += __shfl_down(p1, off);
        p2 += __shfl_down(p2, off);
        p3 += __shfl_down(p3, off);
    }
    const int wave = tid >> 6;
    if ((tid & 63) == 0) {
        red[wave][0] = p0; red[wave][1] = p1;
        red[wave][2] = p2; red[wave][3] = p3;
    }
    __syncthreads();
    if (tid == 0) {
        const float gain = 0.04419417382415922f; // 1/sqrt(512)
        float t[4];
        #pragma unroll
        for (int j = 0; j < 4; ++j) {
            float s = 0.0f;
            #pragma unroll
            for (int v = 0; v < 8; ++v) s += red[v][j];
            t[j] = s * gain + affine_b[j];
        }
        float inv = 1.0f / sqrtf(t[0] * t[0] + t[1] * t[1]);
        float c = t[0] * inv, s = t[1] * inv, tx = t[2] * inv, ty = t[3] * inv;
        par[0] = c;
        par[1] = s;
        par[2] = -c * tx + s * ty;
        par[3] = -s * tx - c * ty;
    }
    __syncthreads();
    const float c_ = par[0], s_ = par[1], tr0 = par[2], tr1 = par[3];
    const int c = tid;
    float fx = freqs[c * 2 + 0], fy = freqs[c * 2 + 1];
    float frx = fx * c_ + fy * s_;
    float fry = -fx * s_ + fy * c_;
    float ph = phases[c] + fx * tr0 + fy * tr1;
    float r = sqrtf(frx * frx + fry * fry);
    float amp = 1.0f - (r - 2.0f) * (1.0f / 30.0f); // (r-BW)/(SR/2-BW)
    amp = fminf(fmaxf(amp, 0.0f), 1.0f);
    frx_o[n * CHN + c] = frx;
    fry_o[n * CHN + c] = fry;
    pha_o[n * CHN + c] = ph;
    amp_o[n * CHN + c] = amp;
}

// ---------------- tables: packed bf16 pairs + weight cvt (no redundant reduction) ----------------
// blocks [0, NB*64): SCA[n][w][c] = pack(amp*sinA, amp*cosA); SCB[n][h][c] = pack(sinB, cosB)
// blocks [NB*64, +512): weight -> bf16 * 1/sqrt(CH)
__global__ __launch_bounds__(512) void table_kernel(
    const float* __restrict__ frx, const float* __restrict__ fry,
    const float* __restrict__ pha, const float* __restrict__ amp,
    const float* __restrict__ wsrc,
    unsigned* __restrict__ SCA, unsigned* __restrict__ SCB,
    __hip_bfloat16* __restrict__ wbf)
{
    const int b = blockIdx.x;
    const int tid = threadIdx.x;
    if (b < NB * 64) {
        const int n = b >> 6;
        const int w = b & 63;
        const int c = tid;
        float fx = frx[n * CHN + c];
        float fy = fry[n * CHN + c];
        float ph = pha[n * CHN + c];
        float a  = amp[n * CHN + c];
        float xs = (float)(2 * w + 1) * (1.0f / 128.0f) - 0.5f; // == ys_w
        size_t idx = ((size_t)(n * 64 + w)) * CHN + c;
        float sA = a * __builtin_amdgcn_sinf(xs * fx);
        float cA = a * __builtin_amdgcn_cosf(xs * fx);
        float bb = xs * fy + ph;
        SCA[idx] = pack_bf(sA, cA);
        SCB[idx] = pack_bf(__builtin_amdgcn_sinf(bb), __builtin_amdgcn_cosf(bb));
    } else {
        int i = (b - NB * 64) * 512 + tid;
        wbf[i] = __float2bfloat16(wsrc[i] * 0.04419417382415922f);
    }
}

// ---------------- fused features + GEMM (R9 exactly — best measured: 103.0 us) ----------------
// 128(m) x 256(k) block tile, BK=64, 256 thr = 4 waves 1(m) x 4(k):
// wave tile 128m x 64k (acc 4x8). Single-buffered swizzled As/Bs, 2 barriers/K-step.
// XCD-bijective n-major block swizzle, packed bf16 tables, setprio around MFMA.
__global__ __launch_bounds__(256, 2) void fused_kernel(
    const unsigned* __restrict__ SCA, const unsigned* __restrict__ SCB,
    const __hip_bfloat16* __restrict__ wbf,
    float* __restrict__ out)
{
    __shared__ __align__(16) __hip_bfloat16 As[128 * 64]; // 16 KB, swizzled
    __shared__ __align__(16) __hip_bfloat16 Bs[256 * 64]; // 32 KB, swizzled

    // XCD-aware bijective swizzle: 2048 blocks, 8 XCDs, 256 per XCD.
    // orig order is n-major -> each XCD works 4 consecutive n's (tables fit its L2).
    const int bid  = blockIdx.x;
    const int orig = (bid & 7) * 256 + (bid >> 3);
    const int n  = orig >> 6;
    const int kb = ((orig >> 5) & 1) * 256;
    const int mb = (orig & 31) * 128;
    const int h0 = mb >> 6;

    const int tid = threadIdx.x;
    const int lane = tid & 63;
    const int wid  = tid >> 6;        // 0..3
    const int ln15 = lane & 15;
    const int hi4  = lane >> 4;
    const int wk   = wid * 64;        // k offset of wave within block k-tile

    const int cc0 = (tid & 7) * 8;    // c-subchunk within 64
    const int rb  = tid >> 3;         // 0..31

    const unsigned* pA0 = SCA + ((size_t)(n * 64 + rb)) * CHN + cc0;       // w = rb
    const unsigned* pA1 = pA0 + 32 * CHN;                                   // w = rb+32
    const unsigned* pB0 = SCB + ((size_t)(n * 64 + h0)) * CHN + cc0;        // h = h0
    const unsigned* pB1 = pB0 + CHN;                                        // h = h0+1

    f32x4 acc[4][8];
    #pragma unroll
    for (int a = 0; a < 4; ++a)
        #pragma unroll
        for (int b = 0; b < 8; ++b)
            acc[a][b] = (f32x4)0.0f;

    #pragma unroll 1
    for (int kc = 0; kc < 8; ++kc) {
        const int c0 = kc * 64;
        __syncthreads(); // prev MFMA frag reads done

        // stage Bs[256][64]: linear LDS dest, pre-swizzled global source (8 units/thread)
        #pragma unroll
        for (int u = 0; u < 8; ++u) {
            int unit = u * 256 + tid;
            int row = unit >> 3;
            int cbyte = ((unit & 7) << 4) ^ ((row & 7) << 4);
            const __hip_bfloat16* src = wbf + (size_t)(kb + row) * CHN + c0 + (cbyte >> 1);
            char* ldsbase = (char*)Bs + (u * 256 + (wid << 6)) * 16; // wave-uniform
            __builtin_amdgcn_global_load_lds(
                (const __attribute__((address_space(1))) unsigned int*)src,
                (__attribute__((address_space(3))) unsigned int*)ldsbase, 16, 0, 0);
        }

        // features: f = sA*cB + cA*sB from packed bf16-pair tables (8 uint4 loads)
        uint4v A00 = *(const uint4v*)(pA0 + c0), A01 = *(const uint4v*)(pA0 + c0 + 4);
        uint4v A10 = *(const uint4v*)(pA1 + c0), A11 = *(const uint4v*)(pA1 + c0 + 4);
        uint4v B00 = *(const uint4v*)(pB0 + c0), B01 = *(const uint4v*)(pB0 + c0 + 4);
        uint4v B10 = *(const uint4v*)(pB1 + c0), B11 = *(const uint4v*)(pB1 + c0 + 4);
        #pragma unroll
        for (int i = 0; i < 4; ++i) {
            int m = rb + i * 32;
            uint4v Aa = (i & 1) ? A10 : A00, Ab = (i & 1) ? A11 : A01;
            uint4v Ba = (i >> 1) ? B10 : B00, Bb = (i >> 1) ? B11 : B01;
            union { __hip_bfloat16 h[8]; int4v v; } t;
            #pragma unroll
            for (int j = 0; j < 4; ++j)
                t.h[j] = __float2bfloat16(
                    lo16f(Aa[j]) * hi16f(Ba[j]) + hi16f(Aa[j]) * lo16f(Ba[j]));
            #pragma unroll
            for (int j = 0; j < 4; ++j)
                t.h[4 + j] = __float2bfloat16(
                    lo16f(Ab[j]) * hi16f(Bb[j]) + hi16f(Ab[j]) * lo16f(Bb[j]));
            *(int4v*)((char*)As + m * 128 + ((cc0 * 2) ^ ((m & 7) << 4))) = t.v;
        }
        __syncthreads(); // As visible + vmcnt drained (Bs complete)

        // MFMA: 64 MFMA per wave-kc from 24 ds_read_b128
        #pragma unroll
        for (int kk = 0; kk < 2; ++kk) {
            short8 wf[4], ff[8];
            #pragma unroll
            for (int ki = 0; ki < 4; ++ki) {
                int row = wk + ki * 16 + ln15;
                wf[ki] = *(const short8*)((char*)Bs + row * 128 +
                          (((kk * 32 + hi4 * 8) * 2) ^ ((row & 7) << 4)));
            }
            #pragma unroll
            for (int mj = 0; mj < 8; ++mj) {
                int m = mj * 16 + ln15;
                ff[mj] = *(const short8*)((char*)As + m * 128 +
                          (((kk * 32 + hi4 * 8) * 2) ^ ((m & 7) << 4)));
            }
            __builtin_amdgcn_s_setprio(1);
            #pragma unroll
            for (int ki = 0; ki < 4; ++ki)
                #pragma unroll
                for (int mj = 0; mj < 8; ++mj)
                    acc[ki][mj] = __builtin_amdgcn_mfma_f32_16x16x32_bf16(
                        wf[ki], ff[mj], acc[ki][mj], 0, 0, 0);
            __builtin_amdgcn_s_setprio(0);
        }
    }

    // epilogue: out[n][k][hw], D col (ln15) = m -> coalesced
    #pragma unroll
    for (int ki = 0; ki < 4; ++ki) {
        #pragma unroll
        for (int mj = 0; mj < 8; ++mj) {
            int kg = kb + wk + ki * 16 + hi4 * 4;
            int mg = mb + mj * 16 + ln15;
            float* op = out + ((size_t)n * CHN + kg) * MTOT + mg;
            #pragma unroll
            for (int r = 0; r < 4; ++r)
                op[(size_t)r * MTOT] = acc[ki][mj][r];
        }
    }
}

extern "C" void kernel_launch(void* const* d_in, const int* in_sizes, int n_in,
                              void* d_out, int out_size, void* d_ws, size_t ws_size,
                              hipStream_t stream) {
    const float* w        = (const float*)d_in[0];
    const float* affine_w = (const float*)d_in[1];
    const float* affine_b = (const float*)d_in[2];
    const float* weight   = (const float*)d_in[3];
    const float* freqs    = (const float*)d_in[4];
    const float* phases   = (const float*)d_in[5];
    float* out = (float*)d_out;

    char* ws = (char*)d_ws;
    __hip_bfloat16* wbf = (__hip_bfloat16*)(ws);                 // 512 KB
    unsigned* SCA = (unsigned*)(ws + (1u << 20));                // 4 MB
    unsigned* SCB = (unsigned*)(ws + (1u << 20) + (4u << 20));   // 4 MB
    float* frx = (float*)(ws + (9u << 20));                      // 64 KB each
    float* fry = (float*)(ws + (9u << 20) + 65536);
    float* pha = (float*)(ws + (9u << 20) + 131072);
    float* amp = (float*)(ws + (9u << 20) + 196608);

    setup_kernel<<<NB, 512, 0, stream>>>(w, affine_w, affine_b, freqs, phases,
                                         frx, fry, pha, amp);
    table_kernel<<<NB * 64 + (CHN * CHN) / 512, 512, 0, stream>>>(
        frx, fry, pha, amp, weight, SCA, SCB, wbf);

    fused_kernel<<<2048, 256, 0, stream>>>(SCA, SCB, wbf, out);
}